// Round 1
// baseline (2470.865 us; speedup 1.0000x reference)
//
#include <hip/hip_runtime.h>
#include <cstdint>
#include <cstddef>

#define GRID_DIM 160
#define GRID_VOX (GRID_DIM * GRID_DIM * GRID_DIM)
#define CIN 64
#define COUT 96
#define NK 27

// ---------------------------------------------------------------------------
// Kernel 1: scatter point indices into the dense voxel grid.
// Grid is pre-memset to -1 (0xFF bytes). atomicMax => largest index wins,
// matching XLA scatter "last update wins" for duplicate coordinates.
// ---------------------------------------------------------------------------
__global__ __launch_bounds__(256) void scatter_kernel(
    const int* __restrict__ coords, int* __restrict__ grid, int N)
{
    int i = blockIdx.x * 256 + threadIdx.x;
    if (i >= N) return;
    int c0 = coords[i * 3 + 0];
    int c1 = coords[i * 3 + 1];
    int c2 = coords[i * 3 + 2];
    int lin = (c0 * GRID_DIM + c1) * GRID_DIM + c2;
    atomicMax(&grid[lin], i);
}

// ---------------------------------------------------------------------------
// Kernel 2: transpose weight [27][64][96] -> [27][96][64] so each output
// channel's reduction row is contiguous (float4-loadable per lane).
// ---------------------------------------------------------------------------
__global__ __launch_bounds__(256) void transpose_w(
    const float* __restrict__ w, float* __restrict__ wt)
{
    int idx = blockIdx.x * 256 + threadIdx.x;
    if (idx >= NK * CIN * COUT) return;
    int k   = idx / (CIN * COUT);
    int r   = idx - k * (CIN * COUT);
    int cin = r / COUT;
    int c   = r - cin * COUT;
    wt[((size_t)k * COUT + c) * CIN + cin] = w[idx];
}

// ---------------------------------------------------------------------------
// Kernel 3: fused subm-conv + LayerNorm + ReLU.
// One point per 32-lane half-wave. Lane h owns couts {h, h+32, h+64}.
// Lanes 0..26 probe the 27 neighbor offsets; ballot-compact the active set;
// loop only over active entries (preserves ~2.6/27 sparsity).
// ---------------------------------------------------------------------------
__global__ __launch_bounds__(256) void conv_ln_relu(
    const float* __restrict__ feat,    // [N,64]
    const int*   __restrict__ coords,  // [N,3]
    const float* __restrict__ wt,      // [27,96,64] transposed
    const float* __restrict__ bias,    // [96]
    const float* __restrict__ gamma,   // [96]
    const float* __restrict__ beta,    // [96]
    const int*   __restrict__ grid,    // [160^3]
    float*       __restrict__ out,     // [N,96]
    int N)
{
    int tid = blockIdx.x * blockDim.x + threadIdx.x;
    int p = tid >> 5;                  // point id: one per half-wave
    if (p >= N) return;
    int lane = threadIdx.x & 63;
    int h = threadIdx.x & 31;          // lane within half
    bool hiHalf = lane >= 32;

    int c0 = coords[p * 3 + 0];
    int c1 = coords[p * 3 + 1];
    int c2 = coords[p * 3 + 2];

    // Phase A: neighbor probe (lanes 0..26 of each half)
    int nidx = -1;
    if (h < NK) {
        int dz = h / 9 - 1;
        int dy = (h / 3) % 3 - 1;
        int dx = h % 3 - 1;
        int a0 = c0 + dz, a1 = c1 + dy, a2 = c2 + dx;
        if ((unsigned)a0 < GRID_DIM && (unsigned)a1 < GRID_DIM &&
            (unsigned)a2 < GRID_DIM) {
            nidx = grid[(a0 * GRID_DIM + a1) * GRID_DIM + a2];
        }
    }
    unsigned long long ball = __ballot(nidx >= 0);
    unsigned m = hiHalf ? (unsigned)(ball >> 32) : (unsigned)ball;

    // Phase B: accumulate over active neighbor entries
    float acc0 = bias[h];
    float acc1 = bias[h + 32];
    float acc2 = bias[h + 64];

    while (m) {
        int b = __ffs(m) - 1;          // kernel offset index (uniform per half)
        m &= m - 1;
        int src = __shfl(nidx, b + (hiHalf ? 32 : 0));

        const float4* fp = (const float4*)(feat + (size_t)src * CIN);
        const float4* w0 = (const float4*)(wt + ((size_t)b * COUT + h) * CIN);
        const float4* w1 = w0 + (32 * CIN / 4);
        const float4* w2 = w0 + (64 * CIN / 4);

        #pragma unroll 8
        for (int ci = 0; ci < CIN / 4; ++ci) {
            float4 f  = fp[ci];
            float4 wa = w0[ci];
            float4 wb = w1[ci];
            float4 wc = w2[ci];
            acc0 = fmaf(f.w, wa.w, fmaf(f.z, wa.z, fmaf(f.y, wa.y, fmaf(f.x, wa.x, acc0))));
            acc1 = fmaf(f.w, wb.w, fmaf(f.z, wb.z, fmaf(f.y, wb.y, fmaf(f.x, wb.x, acc1))));
            acc2 = fmaf(f.w, wc.w, fmaf(f.z, wc.z, fmaf(f.y, wc.y, fmaf(f.x, wc.x, acc2))));
        }
    }

    // Phase C: LayerNorm over 96 channels (3 per lane, 32-lane half reduce)
    float s  = acc0 + acc1 + acc2;
    float s2 = acc0 * acc0 + acc1 * acc1 + acc2 * acc2;
    #pragma unroll
    for (int off = 16; off >= 1; off >>= 1) {
        s  += __shfl_xor(s, off);      // xor mask < 32 stays within the half
        s2 += __shfl_xor(s2, off);
    }
    float mu  = s * (1.0f / COUT);
    float var = s2 * (1.0f / COUT) - mu * mu;
    float rs  = rsqrtf(var + 1e-5f);

    float o0 = (acc0 - mu) * rs * gamma[h]      + beta[h];
    float o1 = (acc1 - mu) * rs * gamma[h + 32] + beta[h + 32];
    float o2 = (acc2 - mu) * rs * gamma[h + 64] + beta[h + 64];

    float* op = out + (size_t)p * COUT;
    op[h]      = o0 > 0.0f ? o0 : 0.0f;
    op[h + 32] = o1 > 0.0f ? o1 : 0.0f;
    op[h + 64] = o2 > 0.0f ? o2 : 0.0f;
}

// ---------------------------------------------------------------------------
extern "C" void kernel_launch(void* const* d_in, const int* in_sizes, int n_in,
                              void* d_out, int out_size, void* d_ws, size_t ws_size,
                              hipStream_t stream)
{
    const float* feat   = (const float*)d_in[0];
    const int*   coords = (const int*)d_in[1];
    const float* weight = (const float*)d_in[2];
    const float* bias   = (const float*)d_in[3];
    const float* gamma  = (const float*)d_in[4];
    const float* beta   = (const float*)d_in[5];
    float* out = (float*)d_out;

    int N = in_sizes[0] / CIN;   // 262144

    // Workspace layout:
    //   [0, GRID_VOX*4)                       : voxel grid (int32)
    //   [GRID_VOX*4, +27*96*64*4)             : transposed weight
    int*   grid_ws = (int*)d_ws;
    float* wt      = (float*)((char*)d_ws + (size_t)GRID_VOX * sizeof(int));

    // 1. grid = -1 (0xFF bytes)
    hipMemsetAsync(grid_ws, 0xFF, (size_t)GRID_VOX * sizeof(int), stream);

    // 2. scatter point indices (max-index wins)
    scatter_kernel<<<(N + 255) / 256, 256, 0, stream>>>(coords, grid_ws, N);

    // 3. transpose weights
    {
        int total = NK * CIN * COUT;
        transpose_w<<<(total + 255) / 256, 256, 0, stream>>>(weight, wt);
    }

    // 4. fused conv + LN + ReLU: one point per half-wave (8 points / 256-thr block)
    {
        long long threads = (long long)N * 32;
        int blocks = (int)((threads + 255) / 256);
        conv_ln_relu<<<blocks, 256, 0, stream>>>(feat, coords, wt, bias, gamma,
                                                 beta, grid_ws, out, N);
    }
}

// Round 2
// 986.416 us; speedup vs baseline: 2.5049x; 2.5049x over previous
//
#include <hip/hip_runtime.h>
#include <cstdint>
#include <cstddef>

#define GRID_DIM 160
#define GRID_VOX (GRID_DIM * GRID_DIM * GRID_DIM)
#define CIN 64
#define COUT 96
#define NK 27

// ---------------------------------------------------------------------------
// Kernel 1: scatter point indices into the dense voxel grid.
// Grid pre-memset to -1. atomicMax => largest index wins (XLA last-wins).
// ---------------------------------------------------------------------------
__global__ __launch_bounds__(256) void scatter_kernel(
    const int* __restrict__ coords, int* __restrict__ grid, int N)
{
    int i = blockIdx.x * 256 + threadIdx.x;
    if (i >= N) return;
    int c0 = coords[i * 3 + 0];
    int c1 = coords[i * 3 + 1];
    int c2 = coords[i * 3 + 2];
    int lin = (c0 * GRID_DIM + c1) * GRID_DIM + c2;
    atomicMax(&grid[lin], i);
}

// ---------------------------------------------------------------------------
// Kernel 2: repack weight [27][64][96] -> [27][16][96][4]:
//   wt2[k][ci4][c][j] = w[k][ci4*4+j][c]
// Lane h's float4 for (k, ci4, cout c) sits at 16B lane stride -> coalesced.
// ---------------------------------------------------------------------------
__global__ __launch_bounds__(256) void repack_w(
    const float* __restrict__ w, float* __restrict__ wt2)
{
    int idx = blockIdx.x * 256 + threadIdx.x;
    if (idx >= NK * CIN * COUT) return;
    int k   = idx / (CIN * COUT);
    int r   = idx - k * (CIN * COUT);
    int ci  = r / COUT;          // input channel
    int c   = r - ci * COUT;     // output channel
    int ci4 = ci >> 2;
    int j   = ci & 3;
    wt2[(((size_t)k * 16 + ci4) * COUT + c) * 4 + j] = w[idx];
}

// ---------------------------------------------------------------------------
// Kernel 3: fused subm-conv + LayerNorm + ReLU.
// One point per 32-lane half-wave; lane h owns couts {h, h+32, h+64}.
// ---------------------------------------------------------------------------
__global__ __launch_bounds__(256) void conv_ln_relu(
    const float* __restrict__ feat,    // [N,64]
    const int*   __restrict__ coords,  // [N,3]
    const float* __restrict__ wt2,     // [27][16][96][4] repacked
    const float* __restrict__ bias,    // [96]
    const float* __restrict__ gamma,   // [96]
    const float* __restrict__ beta,    // [96]
    const int*   __restrict__ grid,    // [160^3]
    float*       __restrict__ out,     // [N,96]
    int N)
{
    int tid = blockIdx.x * blockDim.x + threadIdx.x;
    int p = tid >> 5;                  // point id: one per half-wave
    if (p >= N) return;
    int lane = threadIdx.x & 63;
    int h = threadIdx.x & 31;          // lane within half
    bool hiHalf = lane >= 32;

    int c0 = coords[p * 3 + 0];
    int c1 = coords[p * 3 + 1];
    int c2 = coords[p * 3 + 2];

    // Phase A: neighbor probe (lanes 0..26 of each half)
    int nidx = -1;
    if (h < NK) {
        int dz = h / 9 - 1;
        int dy = (h / 3) % 3 - 1;
        int dx = h % 3 - 1;
        int a0 = c0 + dz, a1 = c1 + dy, a2 = c2 + dx;
        if ((unsigned)a0 < GRID_DIM && (unsigned)a1 < GRID_DIM &&
            (unsigned)a2 < GRID_DIM) {
            nidx = grid[(a0 * GRID_DIM + a1) * GRID_DIM + a2];
        }
    }
    unsigned long long ball = __ballot(nidx >= 0);
    unsigned m = hiHalf ? (unsigned)(ball >> 32) : (unsigned)ball;

    // Phase B: accumulate over active neighbor entries
    float acc0 = bias[h];
    float acc1 = bias[h + 32];
    float acc2 = bias[h + 64];

    while (m) {
        int b = __ffs(m) - 1;          // kernel offset index (uniform per half)
        m &= m - 1;
        int src = __shfl(nidx, b + (hiHalf ? 32 : 0));

        const float4* fp = (const float4*)(feat + (size_t)src * CIN);
        const float4* wp = (const float4*)(wt2 + (size_t)b * 16 * COUT * 4);

        #pragma unroll 4
        for (int ci4 = 0; ci4 < 16; ++ci4) {
            float4 f  = fp[ci4];
            float4 wa = wp[ci4 * COUT + h];
            float4 wb = wp[ci4 * COUT + h + 32];
            float4 wc = wp[ci4 * COUT + h + 64];
            acc0 = fmaf(f.w, wa.w, fmaf(f.z, wa.z, fmaf(f.y, wa.y, fmaf(f.x, wa.x, acc0))));
            acc1 = fmaf(f.w, wb.w, fmaf(f.z, wb.z, fmaf(f.y, wb.y, fmaf(f.x, wb.x, acc1))));
            acc2 = fmaf(f.w, wc.w, fmaf(f.z, wc.z, fmaf(f.y, wc.y, fmaf(f.x, wc.x, acc2))));
        }
    }

    // Phase C: LayerNorm over 96 channels (3 per lane, 32-lane half reduce)
    float s  = acc0 + acc1 + acc2;
    float s2 = acc0 * acc0 + acc1 * acc1 + acc2 * acc2;
    #pragma unroll
    for (int off = 16; off >= 1; off >>= 1) {
        s  += __shfl_xor(s, off);      // xor mask < 32 stays within the half
        s2 += __shfl_xor(s2, off);
    }
    float mu  = s * (1.0f / COUT);
    float var = s2 * (1.0f / COUT) - mu * mu;
    float rs  = rsqrtf(var + 1e-5f);

    float o0 = (acc0 - mu) * rs * gamma[h]      + beta[h];
    float o1 = (acc1 - mu) * rs * gamma[h + 32] + beta[h + 32];
    float o2 = (acc2 - mu) * rs * gamma[h + 64] + beta[h + 64];

    float* op = out + (size_t)p * COUT;
    op[h]      = o0 > 0.0f ? o0 : 0.0f;
    op[h + 32] = o1 > 0.0f ? o1 : 0.0f;
    op[h + 64] = o2 > 0.0f ? o2 : 0.0f;
}

// ---------------------------------------------------------------------------
extern "C" void kernel_launch(void* const* d_in, const int* in_sizes, int n_in,
                              void* d_out, int out_size, void* d_ws, size_t ws_size,
                              hipStream_t stream)
{
    const float* feat   = (const float*)d_in[0];
    const int*   coords = (const int*)d_in[1];
    const float* weight = (const float*)d_in[2];
    const float* bias   = (const float*)d_in[3];
    const float* gamma  = (const float*)d_in[4];
    const float* beta   = (const float*)d_in[5];
    float* out = (float*)d_out;

    int N = in_sizes[0] / CIN;   // 262144

    // Workspace layout:
    //   [0, GRID_VOX*4)            : voxel grid (int32)
    //   [GRID_VOX*4, +27*64*96*4)  : repacked weight
    int*   grid_ws = (int*)d_ws;
    float* wt2     = (float*)((char*)d_ws + (size_t)GRID_VOX * sizeof(int));

    hipMemsetAsync(grid_ws, 0xFF, (size_t)GRID_VOX * sizeof(int), stream);

    scatter_kernel<<<(N + 255) / 256, 256, 0, stream>>>(coords, grid_ws, N);

    {
        int total = NK * CIN * COUT;
        repack_w<<<(total + 255) / 256, 256, 0, stream>>>(weight, wt2);
    }

    {
        long long threads = (long long)N * 32;
        int blocks = (int)((threads + 255) / 256);
        conv_ln_relu<<<blocks, 256, 0, stream>>>(feat, coords, wt2, bias, gamma,
                                                 beta, grid_ws, out, N);
    }
}